// Round 3
// baseline (430.607 us; speedup 1.0000x reference)
//
#include <hip/hip_runtime.h>
#include <hip/hip_bf16.h>
#include <cstdint>
#include <type_traits>

// Problem constants (reference: N=8192, D=2048, M=512, E=4, SCALE=1)
#define N_TOK 8192
#define DDIM  2048
#define MDIM  512
#define NEXP  4

typedef __bf16 bf16x4 __attribute__((ext_vector_type(4)));
typedef __bf16 bf16x8 __attribute__((ext_vector_type(8)));
typedef float  f32x4  __attribute__((ext_vector_type(4)));

// ---------------------------------------------------------------------------
// Scratch in module device globals (fully rewritten every call).
// ---------------------------------------------------------------------------
__device__ int g_counts[NEXP];
__device__ int g_idx[NEXP * N_TOK];
__device__ __align__(16) __hip_bfloat16 g_H[(size_t)N_TOK * MDIM];          // 8 MB hidden acts
__device__ __align__(16) __hip_bfloat16 g_Xb[(size_t)N_TOK * DDIM];         // 32 MB x in bf16
__device__ __align__(16) __hip_bfloat16 g_W1b[(size_t)NEXP * MDIM * DDIM];  // 8 MB
__device__ __align__(16) __hip_bfloat16 g_W2b[(size_t)NEXP * DDIM * MDIM];  // 8 MB

__global__ void zero_counts_kernel() {
    if (threadIdx.x < NEXP) g_counts[threadIdx.x] = 0;
}

// ---------------------------------------------------------------------------
// Bucket tokens by expert — wave-aggregated atomics (verified in prior rounds).
// ---------------------------------------------------------------------------
__global__ void bucket_kernel(const void* __restrict__ domv) {
    const int i    = blockIdx.x * blockDim.x + threadIdx.x;
    const int lane = threadIdx.x & 63;

    // dtype detect: if the first 64 int64-views are all in [0,NEXP), it's int64
    const long long* d64 = (const long long*)domv;
    long long probe = d64[lane];
    bool mode64 = (__ballot(probe >= 0 && probe < NEXP) == ~0ull);

    const int e = mode64 ? (int)d64[i] : ((const int*)domv)[i];

#pragma unroll
    for (int ex = 0; ex < NEXP; ++ex) {
        unsigned long long m = __ballot(e == ex);
        if (m == 0) continue;                    // wave-uniform branch
        int cnt    = __popcll(m);
        int leader = __ffsll((long long)m) - 1;
        int base   = 0;
        if (lane == leader) base = atomicAdd(&g_counts[ex], cnt);
        base = __shfl(base, leader);
        if (e == ex) {
            int prefix = __popcll(m & ((1ull << lane) - 1ull));
            g_idx[ex * N_TOK + base + prefix] = i;
        }
    }
}

// ---------------------------------------------------------------------------
// fp32 -> bf16 pre-pass for x, W1, W2 (one launch, 3 grid-y segments).
// ---------------------------------------------------------------------------
__global__ __launch_bounds__(256)
void cvt3_kernel(const float* __restrict__ x,
                 const float* __restrict__ w1,
                 const float* __restrict__ w2) {
    const float* src; __hip_bfloat16* dst; int n8;
    if (blockIdx.y == 0)      { src = x;  dst = g_Xb;  n8 = N_TOK * DDIM / 8; }
    else if (blockIdx.y == 1) { src = w1; dst = g_W1b; n8 = NEXP * MDIM * DDIM / 8; }
    else                      { src = w2; dst = g_W2b; n8 = NEXP * DDIM * MDIM / 8; }
    const int stride = gridDim.x * blockDim.x;
    for (int i = blockIdx.x * blockDim.x + threadIdx.x; i < n8; i += stride) {
        f32x4 a = ((const f32x4*)src)[2 * i];
        f32x4 b = ((const f32x4*)src)[2 * i + 1];
        bf16x8 r;
        r[0] = (__bf16)a[0]; r[1] = (__bf16)a[1]; r[2] = (__bf16)a[2]; r[3] = (__bf16)a[3];
        r[4] = (__bf16)b[0]; r[5] = (__bf16)b[1]; r[6] = (__bf16)b[2]; r[7] = (__bf16)b[3];
        ((bf16x8*)dst)[i] = r;
    }
}

// ---------------------------------------------------------------------------
// global -> LDS direct DMA, 16B per lane. LDS dest must be wave-uniform base
// (HW adds lane*16); global source IS per-lane (gather OK).
// ---------------------------------------------------------------------------
__device__ __forceinline__ void gl16(const __hip_bfloat16* g, __hip_bfloat16* l) {
    __builtin_amdgcn_global_load_lds(
        (const __attribute__((address_space(1))) void*)g,
        (__attribute__((address_space(3))) void*)l,
        16, 0, 0);
}

// counted vmcnt wait (T4): immediate must be a literal -> constexpr dispatch
template <int N>
__device__ __forceinline__ void wait_vm() {
    if constexpr (N == 0)      asm volatile("s_waitcnt vmcnt(0)" ::: "memory");
    else if constexpr (N == 5) asm volatile("s_waitcnt vmcnt(5)" ::: "memory");
    else if constexpr (N == 6) asm volatile("s_waitcnt vmcnt(6)" ::: "memory");
    else if constexpr (N == 8) asm volatile("s_waitcnt vmcnt(8)" ::: "memory");
    else                       asm volatile("s_waitcnt vmcnt(0)" ::: "memory");
}

// ---------------------------------------------------------------------------
// Grouped NT GEMM over expert-gathered rows. 512 threads = 8 waves in a
// (BM/WM) x (BN/WN) grid; wave computes WM x WN via (WM/16)x(WN/16) frags of
// 16x16x32 MFMA with swapped operands (each lane holds 4 consecutive C-cols
// of one token row -> f32x4 epilogue).
//
// Round-3 change: 256-wide tiles (gemm2 256x256 = m201 geometry, gemm1
// 256x64). Round-2 showed MfmaUtil 8.4% with MFMA-busy time == ideal: pure
// latency starvation at 2.1 MFLOP/K-step/CU. 256^2 gives 8.4 MFLOP/K-step/CU
// (4x), 8 waves = 2/SIMD, 1 block/CU, ~256 active blocks = one pass.
//
// Pipeline (T3+T4, unchanged from the round-2 PASSING pattern):
//   prologue: stage(t0->buf0), stage(t1->buf1)      [2*LPS in flight]
//   iter t:   s_waitcnt vmcnt(LPS); s_barrier       (t done, t+1 flying)
//             ds_read + MFMA (buf t&1)
//             s_barrier; stage(t+2 -> buf t&1)
//   last:     vmcnt(0); barrier; compute.
//
// LDS XOR-swizzle (both-sides, rule #21): producer fetches global slot
// (l&7)^(l>>3) into linear LDS; consumer reads slot (ks*4+(lane>>4))^(lane&7).
// Valid because every row-base offset is ==0 mod 8 on both sides.
// ---------------------------------------------------------------------------
template <int BM, int BN, int WM, int WN, int KDIM, int NCOLS,
          bool RELU, bool RESID, typename TC>
__device__ __forceinline__ void gemm_core(const __hip_bfloat16* __restrict__ A,
                                          const __hip_bfloat16* __restrict__ B,
                                          const float* __restrict__ bias,
                                          const float* __restrict__ resid,
                                          TC* __restrict__ C) {
    constexpr int BK    = 64;
    constexpr int NACH  = BM / 64;       // A chunks (each: 64 rows x 64 k)
    constexpr int NBCH  = BN / 64;       // B chunks
    constexpr int LPS   = NACH + NBCH;   // gl16 per wave per stage
    constexpr int NI    = WM / 16;       // row frags per wave
    constexpr int NJ    = WN / 16;       // col frags per wave
    constexpr int WVN   = BN / WN;       // wave-grid cols
    constexpr int NSTEP = KDIM / BK;

    const int e   = blockIdx.z;
    const int rt  = blockIdx.x;            // row (token-slot) tile [fast dim]
    const int ct  = blockIdx.y;            // col tile
    const int cnt = g_counts[e];
    if (rt * BM >= cnt) return;            // uniform across block

    __shared__ __align__(16) __hip_bfloat16 sA[2][BM * BK];
    __shared__ __align__(16) __hip_bfloat16 sB[2][BN * BK];
    __shared__ int sTok[BM];

    const int tid  = threadIdx.x;
    const int wave = tid >> 6;             // 0..7
    const int lane = tid & 63;

    for (int s = tid; s < BM; s += 512) {
        int slot = rt * BM + s;
        sTok[s] = g_idx[e * N_TOK + (slot < cnt ? slot : cnt - 1)];
    }
    __syncthreads();

    // --- staging addresses: chunk q = 64 rows; wave w owns rows q*64+w*8..+8,
    // lane l -> row q*64+w*8+(l>>3), source 16B-slot (l&7)^(l>>3) (pre-swizzle).
    const int srow = wave * 8 + (lane >> 3);
    const int ssl  = ((lane & 7) ^ (lane >> 3)) * 8;   // elems

    const __hip_bfloat16* gA[NACH];
#pragma unroll
    for (int q = 0; q < NACH; ++q)
        gA[q] = A + (size_t)sTok[q * 64 + srow] * KDIM + ssl;

    const size_t bbase = (size_t)e * NCOLS + (size_t)ct * BN;
    const __hip_bfloat16* gB[NBCH];
#pragma unroll
    for (int q = 0; q < NBCH; ++q)
        gB[q] = B + (bbase + (size_t)(q * 64 + srow)) * KDIM + ssl;

    auto stage = [&](int buf, int k0) {
#pragma unroll
        for (int q = 0; q < NACH; ++q)
            gl16(gA[q] + k0, &sA[buf][(q * 64 + wave * 8) * BK]);
#pragma unroll
        for (int q = 0; q < NBCH; ++q)
            gl16(gB[q] + k0, &sB[buf][(q * 64 + wave * 8) * BK]);
    };

    // --- fragment read addresses ---
    const int wm   = (wave / WVN) * WM;        // wave row offset in tile
    const int wn   = (wave % WVN) * WN;        // wave col offset in tile
    const int frow = lane & 15;
    int cof[2];                                // swizzled k-slot (elems) per ks
#pragma unroll
    for (int ks = 0; ks < 2; ++ks)
        cof[ks] = ((ks * 4 + (lane >> 4)) ^ (lane & 7)) * 8;

    f32x4 acc[NI][NJ] = {};

    auto compute = [&](int buf) {
        const __hip_bfloat16* pA = &sA[buf][0];
        const __hip_bfloat16* pB = &sB[buf][0];
#pragma unroll
        for (int ks = 0; ks < 2; ++ks) {
            bf16x8 bfr[NJ];
#pragma unroll
            for (int j = 0; j < NJ; ++j)
                bfr[j] = *(const bf16x8*)&pB[(wn + j * 16 + frow) * BK + cof[ks]];
#pragma unroll
            for (int i = 0; i < NI; ++i) {
                bf16x8 af = *(const bf16x8*)&pA[(wm + i * 16 + frow) * BK + cof[ks]];
#pragma unroll
                for (int j = 0; j < NJ; ++j)   // SWAPPED operands: C^T layout
                    acc[i][j] = __builtin_amdgcn_mfma_f32_16x16x32_bf16(
                        bfr[j], af, acc[i][j], 0, 0, 0);
            }
        }
    };

    stage(0, 0);
    stage(1, BK);

    int cur = 0;
    for (int t = 0; t < NSTEP - 1; ++t) {
        wait_vm<LPS>();                        // tile t done; t+1 stays in flight
        __builtin_amdgcn_s_barrier();
        __builtin_amdgcn_sched_barrier(0);
        compute(cur);
        asm volatile("" ::: "memory");         // pin ds_reads above the barrier
        __builtin_amdgcn_s_barrier();          // all waves done reading buf[cur]
        if (t + 2 < NSTEP) stage(cur, (t + 2) * BK);
        cur ^= 1;
    }
    wait_vm<0>();                              // drain last tile
    __builtin_amdgcn_s_barrier();
    __builtin_amdgcn_sched_barrier(0);
    compute(cur);

    // epilogue — swapped-operand C/D layout: acc[i][j][r]:
    //   token row = wm + i*16 + (lane&15)
    //   C column  = ct*BN + wn + j*16 + (lane>>4)*4 + r
    const int lrow = lane & 15;
    const int lcol = (lane >> 4) * 4;
#pragma unroll
    for (int i = 0; i < NI; ++i) {
        const int rl   = wm + i * 16 + lrow;
        const int slot = rt * BM + rl;
        if (slot < cnt) {
            const int tk = sTok[rl];
#pragma unroll
            for (int j = 0; j < NJ; ++j) {
                const int col = ct * BN + wn + j * 16 + lcol;
                const f32x4 bv = *(const f32x4*)&bias[(size_t)e * NCOLS + col];
                f32x4 v = acc[i][j] + bv;
                if (RELU) {
#pragma unroll
                    for (int r = 0; r < 4; ++r) v[r] = fmaxf(v[r], 0.0f);
                }
                if (RESID) v += *(const f32x4*)&resid[(size_t)tk * NCOLS + col];
                if constexpr (std::is_same<TC, float>::value) {
                    *(f32x4*)&C[(size_t)tk * NCOLS + col] = v;
                } else {
                    bf16x4 h;
                    h[0] = (__bf16)v[0]; h[1] = (__bf16)v[1];
                    h[2] = (__bf16)v[2]; h[3] = (__bf16)v[3];
                    *(bf16x4*)&C[(size_t)tk * NCOLS + col] = h;
                }
            }
        }
    }
}

// GEMM1: H = relu(Xb @ W1b[e]^T + b1[e])   [K=2048, cols=512]
// 256x64 tile, 8 waves (4x2, wave 64x32), LPS=5, LDS 81 KB -> 1 block/CU,
// grid 32x8x4 with ~256 active -> one pass.
__global__ __launch_bounds__(512, 2)
void gemm1_kernel(const float* __restrict__ b1) {
    gemm_core<256, 64, 64, 32, DDIM, MDIM, true, false, __hip_bfloat16>(
        g_Xb, g_W1b, b1, nullptr, g_H);
}

// GEMM2: out = x + H @ W2b[e]^T + b2[e]    [K=512, cols=2048]
// 256x256 tile (m201 geometry), 8 waves (2x4, wave 128x64), LPS=8,
// LDS 129 KB -> 1 block/CU, grid 32x8x4 with ~256 active -> one pass.
__global__ __launch_bounds__(512, 2)
void gemm2_kernel(const float* __restrict__ x,
                  const float* __restrict__ b2,
                  float* __restrict__ out) {
    gemm_core<256, 256, 128, 64, MDIM, DDIM, false, true, float>(
        g_H, g_W2b, b2, x, out);
}

extern "C" void kernel_launch(void* const* d_in, const int* in_sizes, int n_in,
                              void* d_out, int out_size, void* d_ws, size_t ws_size,
                              hipStream_t stream) {
    const float* x  = (const float*)d_in[0];
    const void*  dm = d_in[1];
    const float* W1 = (const float*)d_in[2];
    const float* b1 = (const float*)d_in[3];
    const float* W2 = (const float*)d_in[4];
    const float* b2 = (const float*)d_in[5];
    float* out = (float*)d_out;

    zero_counts_kernel<<<1, 64, 0, stream>>>();
    bucket_kernel<<<N_TOK / 256, 256, 0, stream>>>(dm);
    cvt3_kernel<<<dim3(1024, 3), 256, 0, stream>>>(x, W1, W2);

    gemm1_kernel<<<dim3(N_TOK / 256, MDIM / 64, NEXP), 512, 0, stream>>>(b1);
    gemm2_kernel<<<dim3(N_TOK / 256, DDIM / 256, NEXP), 512, 0, stream>>>(x, b2, out);
}

// Round 4
// 241.811 us; speedup vs baseline: 1.7808x; 1.7808x over previous
//
#include <hip/hip_runtime.h>
#include <hip/hip_bf16.h>
#include <cstdint>
#include <type_traits>

// Problem constants (reference: N=8192, D=2048, M=512, E=4, SCALE=1)
#define N_TOK 8192
#define DDIM  2048
#define MDIM  512
#define NEXP  4
#define PADROWS (N_TOK + NEXP * 256)   // expert ranges padded to 256 -> 9216

typedef __bf16 bf16x4 __attribute__((ext_vector_type(4)));
typedef __bf16 bf16x8 __attribute__((ext_vector_type(8)));
typedef float  f32x4  __attribute__((ext_vector_type(4)));

// ---------------------------------------------------------------------------
// Scratch in module device globals (fully rewritten every call).
// All GEMM-staged tensors are stored K-TILED: [kt][row][64] so that one
// staging chunk (32 rows x 64 k) is a CONTIGUOUS 4KB block -> every
// global_load_lds is a contiguous 1KB burst (rounds 2/3 showed ~12k-cycle
// per-K-step stalls with 8-scattered-line gathers; clean-GEMM references
// with identical schedule but contiguous staging run 3-6x faster).
// ---------------------------------------------------------------------------
__device__ int g_counts[NEXP];
__device__ int g_idx[NEXP * N_TOK];
__device__ __align__(16) __hip_bfloat16 g_Xp[(size_t)(DDIM / 64) * PADROWS * 64];  // 37.7 MB
__device__ __align__(16) __hip_bfloat16 g_Hp[(size_t)(MDIM / 64) * PADROWS * 64];  //  9.4 MB
__device__ __align__(16) __hip_bfloat16 g_W1t[(size_t)NEXP * MDIM * DDIM];         //  8.4 MB
__device__ __align__(16) __hip_bfloat16 g_W2t[(size_t)NEXP * DDIM * MDIM];         //  8.4 MB

__global__ void zero_counts_kernel() {
    if (threadIdx.x < NEXP) g_counts[threadIdx.x] = 0;
}

// ---------------------------------------------------------------------------
// Bucket tokens by expert — wave-aggregated atomics (verified in prior rounds).
// ---------------------------------------------------------------------------
__global__ void bucket_kernel(const void* __restrict__ domv) {
    const int i    = blockIdx.x * blockDim.x + threadIdx.x;
    const int lane = threadIdx.x & 63;

    const long long* d64 = (const long long*)domv;
    long long probe = d64[lane];
    bool mode64 = (__ballot(probe >= 0 && probe < NEXP) == ~0ull);

    const int e = mode64 ? (int)d64[i] : ((const int*)domv)[i];

#pragma unroll
    for (int ex = 0; ex < NEXP; ++ex) {
        unsigned long long m = __ballot(e == ex);
        if (m == 0) continue;
        int cnt    = __popcll(m);
        int leader = __ffsll((long long)m) - 1;
        int base   = 0;
        if (lane == leader) base = atomicAdd(&g_counts[ex], cnt);
        base = __shfl(base, leader);
        if (e == ex) {
            int prefix = __popcll(m & ((1ull << lane) - 1ull));
            g_idx[ex * N_TOK + base + prefix] = i;
        }
    }
}

// ---------------------------------------------------------------------------
// Weight convert + re-tile: W1[e][m][d] -> W1t[(e*32+kt)*512+m][64] (kt=d/64)
//                           W2[e][d][m] -> W2t[(e*8+kt)*2048+d][64] (kt=m/64)
// One streaming pass; a GEMM B-stage chunk becomes contiguous.
// ---------------------------------------------------------------------------
__global__ __launch_bounds__(256)
void cvt_w_kernel(const float* __restrict__ w1, const float* __restrict__ w2) {
    const bool is1 = (blockIdx.y == 0);
    const float* src = is1 ? w1 : w2;
    __hip_bfloat16* dst = is1 ? g_W1t : g_W2t;
    const int total8 = NEXP * MDIM * DDIM / 8;      // same for both
    const int stride = gridDim.x * blockDim.x;
    for (int g8 = blockIdx.x * blockDim.x + threadIdx.x; g8 < total8; g8 += stride) {
        const int e   = g8 >> 17;                   // 131072 groups per expert
        const int rem = g8 & 131071;
        int row, kt, within;
        if (is1) { row = rem >> 8; int d0 = (rem & 255) * 8; kt = d0 >> 6; within = d0 & 63; }
        else     { row = rem >> 6; int m0 = (rem & 63) * 8;  kt = m0 >> 6; within = m0 & 63; }
        const float* s = src + (size_t)g8 * 8;
        f32x4 a = *(const f32x4*)s;
        f32x4 b = *(const f32x4*)(s + 4);
        bf16x8 r;
        r[0] = (__bf16)a[0]; r[1] = (__bf16)a[1]; r[2] = (__bf16)a[2]; r[3] = (__bf16)a[3];
        r[4] = (__bf16)b[0]; r[5] = (__bf16)b[1]; r[6] = (__bf16)b[2]; r[7] = (__bf16)b[3];
        const size_t d = is1 ? (((size_t)(e * 32 + kt) * MDIM + row) * 64 + within)
                             : (((size_t)(e * 8 + kt) * DDIM + row) * 64 + within);
        *(bf16x8*)&dst[d] = r;
    }
}

// ---------------------------------------------------------------------------
// x gather-permute-convert: global slot gs (expert-sorted, 256-padded) gets
// token g_idx[e][gs-off[e]] (clamped dup for pad rows), written K-tiled:
// g_Xp[kt][gs][64]. One block per row; reads/writes fully coalesced.
// ---------------------------------------------------------------------------
__global__ __launch_bounds__(256)
void cvt_xp_kernel(const float* __restrict__ x) {
    int c[NEXP], off[NEXP + 1]; off[0] = 0;
#pragma unroll
    for (int e = 0; e < NEXP; ++e) { c[e] = g_counts[e]; off[e + 1] = off[e] + ((c[e] + 255) & ~255); }

    const int gs = blockIdx.x;
    int e = 0;
#pragma unroll
    for (int t = 0; t < NEXP - 1; ++t) if (gs >= off[t + 1]) e = t + 1;
    if (gs >= off[e + 1]) return;                   // beyond all used rows
    int ls = gs - off[e];
    if (ls >= c[e]) ls = c[e] - 1;                  // pad row: duplicate last
    const int tok = g_idx[e * N_TOK + ls];

    const int d0 = threadIdx.x * 8;
    const float* s = x + (size_t)tok * DDIM + d0;
    f32x4 a = *(const f32x4*)s;
    f32x4 b = *(const f32x4*)(s + 4);
    bf16x8 r;
    r[0] = (__bf16)a[0]; r[1] = (__bf16)a[1]; r[2] = (__bf16)a[2]; r[3] = (__bf16)a[3];
    r[4] = (__bf16)b[0]; r[5] = (__bf16)b[1]; r[6] = (__bf16)b[2]; r[7] = (__bf16)b[3];
    *(bf16x8*)&g_Xp[((size_t)(d0 >> 6) * PADROWS + gs) * 64 + (d0 & 63)] = r;
}

// ---------------------------------------------------------------------------
// global -> LDS direct DMA, 16B per lane (wave-uniform LDS base + lane*16).
// ---------------------------------------------------------------------------
__device__ __forceinline__ void gl16(const __hip_bfloat16* g, __hip_bfloat16* l) {
    __builtin_amdgcn_global_load_lds(
        (const __attribute__((address_space(1))) void*)g,
        (__attribute__((address_space(3))) void*)l,
        16, 0, 0);
}

// counted vmcnt wait (T4): immediate must be a literal -> constexpr dispatch
template <int N>
__device__ __forceinline__ void wait_vm() {
    if constexpr (N == 0)      asm volatile("s_waitcnt vmcnt(0)" ::: "memory");
    else if constexpr (N == 6) asm volatile("s_waitcnt vmcnt(6)" ::: "memory");
    else if constexpr (N == 8) asm volatile("s_waitcnt vmcnt(8)" ::: "memory");
    else                       asm volatile("s_waitcnt vmcnt(0)" ::: "memory");
}

// ---------------------------------------------------------------------------
// Grouped NT GEMM over permuted slot rows. BM=128, BK=64, 256 threads =
// 4 waves (2x2). A is K-tiled [kt][PADROWS][64]; B is K-tiled
// [(e*KTS+kt)][NCOLS][64]. ALL staging loads are contiguous 1KB bursts.
//
// Pipeline (r2-PASSING counted-vmcnt 2-phase, geometry = r2 best):
//   prologue: stage(t0->buf0), stage(t1->buf1)
//   iter t:   s_waitcnt vmcnt(LPS); s_barrier; compute(buf); s_barrier;
//             stage(t+2 -> buf)
//
// LDS XOR-swizzle invariant (verified 0 conflicts r2/r3):
//   LDS[row][s] = global[row][s ^ (row&7)], rows within chunk = wave*8+(l>>3),
//   producer source slot (l&7)^(l>>3); consumer reads slot
//   (ks*4+(lane>>4)) ^ (lane&7). Burst-local permutation only.
//
// MFMA operands SWAPPED (mfma(b,a)): lane holds 4 consecutive C-cols of one
// slot row -> f32x4 epilogue.
// ---------------------------------------------------------------------------
template <int BN, int KDIM, int NCOLS, bool RELU, bool TILEOUT, typename TC>
__device__ __forceinline__ void gemm_core(const __hip_bfloat16* __restrict__ A,
                                          const __hip_bfloat16* __restrict__ B,
                                          const float* __restrict__ bias,
                                          const float* __restrict__ resid,
                                          TC* __restrict__ C) {
    constexpr int BM    = 128;
    constexpr int BK    = 64;
    constexpr int KTS   = KDIM / BK;
    constexpr int NACH  = 4;            // A chunks (32 rows x 64 k each)
    constexpr int NBCH  = BN / 32;      // B chunks
    constexpr int LPS   = NACH + NBCH;
    constexpr int NJ    = BN / 32;      // col frags per wave
    constexpr int NSTEP = KTS;

    const int rt = blockIdx.x;
    const int ct = blockIdx.y;

    int cv[NEXP], off[NEXP + 1]; off[0] = 0;
#pragma unroll
    for (int x = 0; x < NEXP; ++x) { cv[x] = g_counts[x]; off[x + 1] = off[x] + ((cv[x] + 255) & ~255); }
    const int r0 = rt * BM;
    if (r0 >= off[NEXP]) return;        // uniform
    int e = 0;
#pragma unroll
    for (int t = 0; t < NEXP - 1; ++t) if (r0 >= off[t + 1]) e = t + 1;

    __shared__ __align__(16) __hip_bfloat16 sA[2][BM * BK];
    __shared__ __align__(16) __hip_bfloat16 sB[2][BN * BK];
    __shared__ int sTok[BM];

    const int tid  = threadIdx.x;
    const int wave = tid >> 6;
    const int lane = tid & 63;

    if (!TILEOUT) {                     // token map needed only for epilogue
        if (tid < BM) {
            int ls = r0 + tid - off[e];
            sTok[tid] = (ls < cv[e]) ? g_idx[e * N_TOK + ls] : -1;
        }
        __syncthreads();
    }

    const int srow = wave * 8 + (lane >> 3);          // row within 32-row chunk
    const int ssl  = ((lane & 7) ^ (lane >> 3)) * 8;  // swizzled source slot

    auto stage = [&](int buf, int kt) {
#pragma unroll
        for (int q = 0; q < NACH; ++q)
            gl16(A + ((size_t)kt * PADROWS + r0 + q * 32 + srow) * 64 + ssl,
                 &sA[buf][(q * 256 + wave * 64) * 8]);
#pragma unroll
        for (int q = 0; q < NBCH; ++q)
            gl16(B + ((size_t)(e * KTS + kt) * NCOLS + ct * BN + q * 32 + srow) * 64 + ssl,
                 &sB[buf][(q * 256 + wave * 64) * 8]);
    };

    const int wm   = (wave >> 1) * 64;
    const int wn   = (wave & 1) * (BN / 2);
    const int frow = lane & 15;
    int cof[2];
#pragma unroll
    for (int ks = 0; ks < 2; ++ks)
        cof[ks] = ((ks * 4 + (lane >> 4)) ^ (lane & 7)) * 8;

    f32x4 acc[4][NJ] = {};

    auto compute = [&](int buf) {
        const __hip_bfloat16* pA = &sA[buf][0];
        const __hip_bfloat16* pB = &sB[buf][0];
#pragma unroll
        for (int ks = 0; ks < 2; ++ks) {
            bf16x8 bfr[NJ];
#pragma unroll
            for (int j = 0; j < NJ; ++j)
                bfr[j] = *(const bf16x8*)&pB[(wn + j * 16 + frow) * BK + cof[ks]];
#pragma unroll
            for (int i = 0; i < 4; ++i) {
                bf16x8 af = *(const bf16x8*)&pA[(wm + i * 16 + frow) * BK + cof[ks]];
#pragma unroll
                for (int j = 0; j < NJ; ++j)
                    acc[i][j] = __builtin_amdgcn_mfma_f32_16x16x32_bf16(
                        bfr[j], af, acc[i][j], 0, 0, 0);
            }
        }
    };

    stage(0, 0);
    stage(1, 1);

    int cur = 0;
    for (int t = 0; t < NSTEP - 1; ++t) {
        wait_vm<LPS>();
        __builtin_amdgcn_s_barrier();
        __builtin_amdgcn_sched_barrier(0);
        compute(cur);
        asm volatile("" ::: "memory");
        __builtin_amdgcn_s_barrier();
        if (t + 2 < NSTEP) stage(cur, t + 2);
        cur ^= 1;
    }
    wait_vm<0>();
    __builtin_amdgcn_s_barrier();
    __builtin_amdgcn_sched_barrier(0);
    compute(cur);

    // epilogue — swapped-operand layout: acc[i][j][r]:
    //   slot row = r0 + wm + i*16 + (lane&15)
    //   C column = ct*BN + wn + j*16 + (lane>>4)*4 + r
    const int lrow = lane & 15;
    const int lcol = (lane >> 4) * 4;
#pragma unroll
    for (int i = 0; i < 4; ++i) {
        const int rl = wm + i * 16 + lrow;
        const int gs = r0 + rl;
#pragma unroll
        for (int j = 0; j < NJ; ++j) {
            const int col = ct * BN + wn + j * 16 + lcol;
            const f32x4 bv = *(const f32x4*)&bias[(size_t)e * NCOLS + col];
            f32x4 v = acc[i][j] + bv;
            if (RELU) {
#pragma unroll
                for (int r = 0; r < 4; ++r) v[r] = fmaxf(v[r], 0.0f);
            }
            if constexpr (TILEOUT) {
                // write K-tiled slot-order (coalesced, no scatter); pad rows
                // written too (finite dup values) so gemm2 staging is defined
                bf16x4 h;
                h[0] = (__bf16)v[0]; h[1] = (__bf16)v[1];
                h[2] = (__bf16)v[2]; h[3] = (__bf16)v[3];
                *(bf16x4*)&C[((size_t)(col >> 6) * PADROWS + gs) * 64 + (col & 63)] = h;
            } else {
                const int tk = sTok[rl];
                if (tk >= 0) {
                    v += *(const f32x4*)&resid[(size_t)tk * NCOLS + col];
                    *(f32x4*)&C[(size_t)tk * NCOLS + col] = v;
                }
            }
        }
    }
}

// GEMM1: Hp = relu(Xp @ W1t[e]^T + b1[e])  [K=2048, cols=512]
// 128x64, 4 waves, LPS=6, LDS 48KB -> 3 blocks/CU. No token gather anywhere.
__global__ __launch_bounds__(256)
void gemm1_kernel(const float* __restrict__ b1) {
    gemm_core<64, DDIM, MDIM, true, true, __hip_bfloat16>(
        g_Xp, g_W1t, b1, nullptr, g_Hp);
}

// GEMM2: out[tok] = x[tok] + Hp @ W2t[e]^T + b2[e]  [K=512, cols=2048]
// 128x128, 4 waves, LPS=8, LDS 64.5KB -> 2 blocks/CU. Scatter only in epilogue.
__global__ __launch_bounds__(256)
void gemm2_kernel(const float* __restrict__ x,
                  const float* __restrict__ b2,
                  float* __restrict__ out) {
    gemm_core<128, MDIM, DDIM, false, false, float>(
        g_Hp, g_W2t, b2, x, out);
}

extern "C" void kernel_launch(void* const* d_in, const int* in_sizes, int n_in,
                              void* d_out, int out_size, void* d_ws, size_t ws_size,
                              hipStream_t stream) {
    const float* x  = (const float*)d_in[0];
    const void*  dm = d_in[1];
    const float* W1 = (const float*)d_in[2];
    const float* b1 = (const float*)d_in[3];
    const float* W2 = (const float*)d_in[4];
    const float* b2 = (const float*)d_in[5];
    float* out = (float*)d_out;

    zero_counts_kernel<<<1, 64, 0, stream>>>();
    bucket_kernel<<<N_TOK / 256, 256, 0, stream>>>(dm);
    cvt_w_kernel<<<dim3(1024, 2), 256, 0, stream>>>(W1, W2);
    cvt_xp_kernel<<<PADROWS, 256, 0, stream>>>(x);

    gemm1_kernel<<<dim3(PADROWS / 128, MDIM / 64), 256, 0, stream>>>(b1);
    gemm2_kernel<<<dim3(PADROWS / 128, DDIM / 128), 256, 0, stream>>>(x, b2, out);
}